// Round 5
// baseline (46.771 us; speedup 1.0000x reference)
//
#include <hip/hip_runtime.h>

typedef __bf16  bf16x8 __attribute__((ext_vector_type(8)));
typedef short   s16x8  __attribute__((ext_vector_type(8)));
typedef float   f32x4  __attribute__((ext_vector_type(4)));
typedef unsigned short u16;
typedef u16     u16x4  __attribute__((ext_vector_type(4)));
typedef unsigned int u32;

#define B_SZ 4096
#define D_SZ 256

static constexpr float SCALE = (float)(1.4426950408889634 / 0.07); // log2(e)/T
static constexpr float LN2F  = 0.69314718055994531f;

__device__ __forceinline__ u16 f2bf(float f) {
  unsigned u = __float_as_uint(f);
  unsigned r = u + 0x7FFFu + ((u >> 16) & 1u);   // round-nearest-even
  return (u16)(r >> 16);
}
__device__ __forceinline__ float bf2f(u16 h) {
  return __uint_as_float((u32)h << 16);
}

template<bool BF>
__device__ __forceinline__ bf16x8 ld8(const u16* pb, const float* pf) {
  if constexpr (BF) {
    return *(const bf16x8*)pb;
  } else {
    f32x4 a = *(const f32x4*)pf;
    f32x4 b = *(const f32x4*)(pf + 4);
    s16x8 s;
#pragma unroll
    for (int i = 0; i < 4; ++i) { s[i] = (short)f2bf(a[i]); s[i + 4] = (short)f2bf(b[i]); }
    return __builtin_bit_cast(bf16x8, s);
  }
}

__global__ __launch_bounds__(256) void cl_convert(const float* __restrict__ x,
                                                  const float* __restrict__ y,
                                                  u16* __restrict__ xb,
                                                  u16* __restrict__ yb) {
  const int idx = (int)(blockIdx.x * 256 + threadIdx.x) * 4;
  f32x4 vx = *(const f32x4*)(x + idx);
  f32x4 vy = *(const f32x4*)(y + idx);
  u16x4 sx, sy;
#pragma unroll
  for (int i = 0; i < 4; ++i) { sx[i] = f2bf(vx[i]); sy[i] = f2bf(vy[i]); }
  *(u16x4*)(xb + idx) = sx;
  *(u16x4*)(yb + idx) = sy;
}

// Shared GEMM core: 128x128 tile, BK=64, double-buffered LDS via
// global_load_lds (pre-swizzled source), XOR-swizzled ds_read.
// Wave tiling: wave w owns rows [w*32, w*32+32), ALL 128 cols.
// acc[mi][ni]: rows w*32+mi*16+l15 (2nd mfma operand), cols ni*16+lg*4+v.
#define GEMM_CORE(ACC)                                                         \
  __shared__ u16 As[2][128 * 64];                                              \
  __shared__ u16 Bs[2][128 * 64];                                              \
  const int tid  = threadIdx.x;                                                \
  const int lane = tid & 63;                                                   \
  const int wv   = tid >> 6;                                                   \
  const int l15  = lane & 15;                                                  \
  const int lg   = lane >> 4;                                                  \
  int bid = (int)blockIdx.x;                                                   \
  bid = (bid & 7) * 128 + (bid >> 3);      /* XCD swizzle (1024%8==0) */       \
  const int brow = (bid >> 5) << 7;                                            \
  const int bcol = (bid & 31) << 7;                                            \
  const int cb   = bid & 31;                                                   \
  (void)cb;                                                                    \
  auto stage_panel = [&](u16* panel, const u16* src, int row0, int kt) {       \
    _Pragma("unroll")                                                          \
    for (int i = 0; i < 4; ++i) {                                              \
      const int chunk = i * 4 + wv;                                            \
      const int r = chunk * 8 + (lane >> 3);                                   \
      const int cs0 = ((lane & 7) << 4) ^ ((r & 7) << 4);                      \
      const char* g = (const char*)src + ((size_t)(row0 + r) << 9)             \
                      + (kt << 7) + cs0;                                       \
      auto lp = (__attribute__((address_space(3))) u32*)                       \
                  ((char*)panel + chunk * 1024 + lane * 16);                   \
      __builtin_amdgcn_global_load_lds(                                        \
          (const __attribute__((address_space(1))) u32*)g, lp, 16, 0, 0);      \
    }                                                                          \
  };                                                                           \
  stage_panel(As[0], xb, brow, 0);                                             \
  stage_panel(Bs[0], yb, bcol, 0);                                             \
  __syncthreads();                                                             \
  _Pragma("unroll 1")                                                          \
  for (int kt = 0; kt < 4; ++kt) {                                             \
    if (kt < 3) {                                                              \
      stage_panel(As[(kt + 1) & 1], xb, brow, kt + 1);                         \
      stage_panel(Bs[(kt + 1) & 1], yb, bcol, kt + 1);                         \
    }                                                                          \
    const u16* Ap = As[kt & 1];                                                \
    const u16* Bp = Bs[kt & 1];                                                \
    _Pragma("unroll")                                                          \
    for (int ks = 0; ks < 2; ++ks) {                                           \
      bf16x8 Af[2], Bf[8];                                                     \
      _Pragma("unroll")                                                        \
      for (int mi = 0; mi < 2; ++mi) {                                         \
        const int ra = (wv << 5) + (mi << 4) + l15;                            \
        const int ca = ((ks << 6) + (lg << 4)) ^ ((ra & 7) << 4);              \
        Af[mi] = *(const bf16x8*)((const char*)Ap + (ra << 7) + ca);           \
      }                                                                        \
      _Pragma("unroll")                                                        \
      for (int ni = 0; ni < 8; ++ni) {                                         \
        const int rb = (ni << 4) + l15;                                        \
        const int cbb = ((ks << 6) + (lg << 4)) ^ ((rb & 7) << 4);             \
        Bf[ni] = *(const bf16x8*)((const char*)Bp + (rb << 7) + cbb);          \
      }                                                                        \
      _Pragma("unroll")                                                        \
      for (int mi = 0; mi < 2; ++mi)                                           \
        _Pragma("unroll")                                                      \
        for (int ni = 0; ni < 8; ++ni)                                         \
          ACC[mi][ni] = __builtin_amdgcn_mfma_f32_16x16x32_bf16(               \
              Bf[ni], Af[mi], ACC[mi][ni], 0, 0, 0);  /* swapped operands */   \
    }                                                                          \
    __syncthreads();                                                           \
  }

// Pass A: per-(row, col-block) exp2 sums -> T[row*32 + cb]
__global__ __launch_bounds__(256, 2) void cl_gemmA(const u16* __restrict__ xb,
                                                   const u16* __restrict__ yb,
                                                   float* __restrict__ T) {
  f32x4 acc[2][8] = {};
  GEMM_CORE(acc)
#pragma unroll
  for (int mi = 0; mi < 2; ++mi) {
    float rs = 0.f;
#pragma unroll
    for (int ni = 0; ni < 8; ++ni)
#pragma unroll
      for (int v = 0; v < 4; ++v)
        rs += __builtin_amdgcn_exp2f(acc[mi][ni][v] * SCALE);
    rs += __shfl_xor(rs, 16, 64);
    rs += __shfl_xor(rs, 32, 64);               // sum over lg -> full row sum
    if (lg == 0)
      T[(size_t)(brow + (wv << 5) + (mi << 4) + l15) * 32 + cb] = rs;
  }
}

// Pass B: recompute tile, ordered prefix + logs + diag -> per-block partial
__global__ __launch_bounds__(256, 2) void cl_gemmB(const u16* __restrict__ xb,
                                                   const u16* __restrict__ yb,
                                                   const float* __restrict__ T,
                                                   float* __restrict__ partials) {
  f32x4 acc[2][8] = {};
  GEMM_CORE(acc)
  float lacc = 0.f;
#pragma unroll
  for (int mi = 0; mi < 2; ++mi) {
    const int grow = brow + (wv << 5) + (mi << 4) + l15;
    // carry-in: sum of exp-sums of all previous col-blocks for this row
    float carry = 0.f;
    const float* Tp = T + (size_t)grow * 32;
#pragma unroll 4
    for (int c2 = 0; c2 < cb; ++c2) carry += Tp[c2];

    float e[8][4], s4[8], p[8], tot[8];
#pragma unroll
    for (int ni = 0; ni < 8; ++ni) {
      const int col0 = bcol + (ni << 4) + (lg << 2);
#pragma unroll
      for (int v = 0; v < 4; ++v) {
        const float tv = acc[mi][ni][v] * SCALE;
        if (grow == col0 + v) lacc -= (float)(B_SZ - grow) * tv;  // diagonal
        e[ni][v] = __builtin_amdgcn_exp2f(tv);
      }
      s4[ni] = (e[ni][0] + e[ni][1]) + (e[ni][2] + e[ni][3]);
    }
#pragma unroll
    for (int ni = 0; ni < 8; ++ni) {
      const float u1 = __shfl_up(s4[ni], 16, 64);
      const float u2 = __shfl_up(s4[ni], 32, 64);
      const float u3 = __shfl_up(s4[ni], 48, 64);
      p[ni] = (lg >= 1 ? u1 : 0.f) + (lg >= 2 ? u2 : 0.f) + (lg >= 3 ? u3 : 0.f);
      float t2 = s4[ni];
      t2 += __shfl_xor(t2, 16, 64);
      t2 += __shfl_xor(t2, 32, 64);
      tot[ni] = t2;                              // full-ni exp sum (all lg)
    }
    float c = carry;
#pragma unroll
    for (int ni = 0; ni < 8; ++ni) {
      const int col0 = bcol + (ni << 4) + (lg << 2);
      const float K = (float)(B_SZ - 1 - col0);
      float b = c + p[ni];
      b += e[ni][0]; lacc += __builtin_amdgcn_logf(b + K);
      b += e[ni][1]; lacc += __builtin_amdgcn_logf(b + (K - 1.f));
      b += e[ni][2]; lacc += __builtin_amdgcn_logf(b + (K - 2.f));
      b += e[ni][3]; lacc += __builtin_amdgcn_logf(b + (K - 3.f));
      c += tot[ni];
    }
  }
  lacc *= LN2F;

  __shared__ float red2[4];
#pragma unroll
  for (int d = 1; d < 64; d <<= 1) lacc += __shfl_xor(lacc, d, 64);
  if (lane == 0) red2[wv] = lacc;
  __syncthreads();
  if (tid == 0)
    partials[blockIdx.x] = (red2[0] + red2[1]) + (red2[2] + red2[3]);
}

__global__ __launch_bounds__(256) void cl_final(const float* __restrict__ p,
                                                float* __restrict__ out) {
  __shared__ float red[256];
  const int tid = threadIdx.x;
  float s = 0.f;
#pragma unroll
  for (int k = 0; k < 4; ++k) s += p[tid + 256 * k];
  red[tid] = s;
  __syncthreads();
#pragma unroll
  for (int o = 128; o > 0; o >>= 1) {
    if (tid < o) red[tid] += red[tid + o];
    __syncthreads();
  }
  if (tid == 0) out[0] = red[0];
}

// ---------------- Fallback (R1 fused kernel, known-good) -------------------
template<bool BF>
__global__ __launch_bounds__(256) void cl_main(const float* __restrict__ x,
                                               const float* __restrict__ y,
                                               const u16* __restrict__ xb,
                                               const u16* __restrict__ yb,
                                               float* __restrict__ partials) {
  __shared__ float st[16][68];
  __shared__ float red[256];
  const int tid  = threadIdx.x;
  const int lane = tid & 63;
  const int wv   = tid >> 6;
  const int l15  = lane & 15;
  const int lg   = lane >> 4;
  const int i0   = blockIdx.x * 16;

  bf16x8 A[8];
  {
    const size_t base = (size_t)(i0 + l15) * D_SZ + (lg << 3);
#pragma unroll
    for (int ks = 0; ks < 8; ++ks)
      A[ks] = ld8<BF>(xb + base + ks * 32, x + base + ks * 32);
  }

  float lacc = 0.f, carry = 0.f;

  auto load_b = [&](bf16x8 (&F)[8], int t) {
    const size_t jb = (size_t)(t * 64 + (wv << 4) + l15) * D_SZ + (lg << 3);
#pragma unroll
    for (int ks = 0; ks < 8; ++ks)
      F[ks] = ld8<BF>(yb + jb + ks * 32, y + jb + ks * 32);
  };

  auto body = [&](bf16x8 (&F)[8], int t) {
    f32x4 acc = {0.f, 0.f, 0.f, 0.f};
#pragma unroll
    for (int ks = 0; ks < 8; ++ks)
      acc = __builtin_amdgcn_mfma_f32_16x16x32_bf16(A[ks], F[ks], acc, 0, 0, 0);
    __syncthreads();
    const int colg = t * 64 + (wv << 4) + l15;
#pragma unroll
    for (int v = 0; v < 4; ++v) {
      float tv = acc[v] * SCALE;
      const int rowl = (lg << 2) + v;
      if (i0 + rowl == colg) lacc -= (float)(B_SZ - colg) * tv;
      st[rowl][(wv << 4) + l15] = tv;
    }
    __syncthreads();
    const int row = (wv << 2) + lg;
    f32x4 tv4 = *(const f32x4*)&st[row][l15 << 2];
    float e0 = __builtin_amdgcn_exp2f(tv4[0]);
    float e1 = __builtin_amdgcn_exp2f(tv4[1]);
    float e2 = __builtin_amdgcn_exp2f(tv4[2]);
    float e3 = __builtin_amdgcn_exp2f(tv4[3]);
    float p1 = e0 + e1, p2 = p1 + e2, p3 = p2 + e3;
    float s = p3;
#pragma unroll
    for (int d = 1; d < 16; d <<= 1) {
      float u = __shfl_up(s, (unsigned)d, 16);
      if (l15 >= d) s += u;
    }
    const float base = carry + (s - p3);
    const float c0 = (float)(B_SZ - 1 - (t * 64 + (l15 << 2)));
    lacc += __builtin_amdgcn_logf(base + e0 + c0)
          + __builtin_amdgcn_logf(base + p1 + (c0 - 1.f))
          + __builtin_amdgcn_logf(base + p2 + (c0 - 2.f))
          + __builtin_amdgcn_logf(base + p3 + (c0 - 3.f));
    carry += __shfl(s, 15, 16);
  };

  bf16x8 B0[8], B1[8];
  load_b(B0, 0);
#pragma unroll 1
  for (int t2 = 0; t2 < 32; ++t2) {
    const int t0 = t2 * 2;
    load_b(B1, t0 + 1);
    body(B0, t0);
    if (t0 + 2 < 64) load_b(B0, t0 + 2);
    body(B1, t0 + 1);
  }

  red[tid] = lacc * LN2F;
  __syncthreads();
#pragma unroll
  for (int o = 128; o > 0; o >>= 1) {
    if (tid < o) red[tid] += red[tid + o];
    __syncthreads();
  }
  if (tid == 0) partials[blockIdx.x] = red[0];
}

__global__ __launch_bounds__(256) void cl_reduce(const float* __restrict__ p,
                                                 float* __restrict__ out) {
  __shared__ float red[256];
  const int tid = threadIdx.x;
  red[tid] = p[tid];
  __syncthreads();
#pragma unroll
  for (int o = 128; o > 0; o >>= 1) {
    if (tid < o) red[tid] += red[tid + o];
    __syncthreads();
  }
  if (tid == 0) out[0] = red[0];
}

extern "C" void kernel_launch(void* const* d_in, const int* in_sizes, int n_in,
                              void* d_out, int out_size, void* d_ws, size_t ws_size,
                              hipStream_t stream) {
  const float* x = (const float*)d_in[0];
  const float* y = (const float*)d_in[1];
  float* out = (float*)d_out;
  const size_t BD = (size_t)B_SZ * D_SZ;

  // Layout: partials(16KB) | T(512KB) | xb(2MB) | yb(2MB)  — no Sl matrix.
  float* partials = (float*)d_ws;
  float* T  = (float*)((char*)d_ws + 16384);
  u16* xb = (u16*)((char*)d_ws + 16384 + 524288);
  u16* yb = xb + BD;
  const size_t need = 16384 + 524288 + 4 * BD;

  if (ws_size >= need) {
    cl_convert<<<(int)(BD / 1024), 256, 0, stream>>>(x, y, xb, yb);
    cl_gemmA<<<1024, 256, 0, stream>>>(xb, yb, T);
    cl_gemmB<<<1024, 256, 0, stream>>>(xb, yb, T, partials);
    cl_final<<<1, 256, 0, stream>>>(partials, out);
  } else {
    // Fallback: R1 fused path (original layout: partials@0, xb@4KB)
    float* fpart = (float*)d_ws;
    u16* fxb = (u16*)((char*)d_ws + 4096);
    u16* fyb = fxb + BD;
    const size_t fneed = 4096 + 4 * BD;
    if (ws_size >= fneed) {
      cl_convert<<<(int)(BD / 1024), 256, 0, stream>>>(x, y, fxb, fyb);
      cl_main<true><<<B_SZ / 16, 256, 0, stream>>>(x, y, fxb, fyb, fpart);
    } else {
      cl_main<false><<<B_SZ / 16, 256, 0, stream>>>(x, y, fxb, fyb, fpart);
    }
    cl_reduce<<<1, 256, 0, stream>>>(fpart, out);
  }
}

// Round 6
// 40.567 us; speedup vs baseline: 1.1529x; 1.1529x over previous
//
#include <hip/hip_runtime.h>

typedef __bf16  bf16x8 __attribute__((ext_vector_type(8)));
typedef short   s16x8  __attribute__((ext_vector_type(8)));
typedef float   f32x4  __attribute__((ext_vector_type(4)));
typedef unsigned short u16;
typedef u16     u16x4  __attribute__((ext_vector_type(4)));
typedef unsigned int u32;

#define B_SZ 4096
#define D_SZ 256

static constexpr float SCALE = (float)(1.4426950408889634 / 0.07); // log2(e)/T
static constexpr float LN2F  = 0.69314718055994531f;

__device__ __forceinline__ u16 f2bf(float f) {
  unsigned u = __float_as_uint(f);
  unsigned r = u + 0x7FFFu + ((u >> 16) & 1u);   // round-nearest-even
  return (u16)(r >> 16);
}
__device__ __forceinline__ float bf2f(u16 h) {
  return __uint_as_float((u32)h << 16);
}

template<bool BF>
__device__ __forceinline__ bf16x8 ld8(const u16* pb, const float* pf) {
  if constexpr (BF) {
    return *(const bf16x8*)pb;
  } else {
    f32x4 a = *(const f32x4*)pf;
    f32x4 b = *(const f32x4*)(pf + 4);
    s16x8 s;
#pragma unroll
    for (int i = 0; i < 4; ++i) { s[i] = (short)f2bf(a[i]); s[i + 4] = (short)f2bf(b[i]); }
    return __builtin_bit_cast(bf16x8, s);
  }
}

__global__ __launch_bounds__(256) void cl_convert(const float* __restrict__ x,
                                                  const float* __restrict__ y,
                                                  u16* __restrict__ xb,
                                                  u16* __restrict__ yb) {
  const int idx = (int)(blockIdx.x * 256 + threadIdx.x) * 4;
  f32x4 vx = *(const f32x4*)(x + idx);
  f32x4 vy = *(const f32x4*)(y + idx);
  u16x4 sx, sy;
#pragma unroll
  for (int i = 0; i < 4; ++i) { sx[i] = f2bf(vx[i]); sy[i] = f2bf(vy[i]); }
  *(u16x4*)(xb + idx) = sx;
  *(u16x4*)(yb + idx) = sy;
}

// ---------------- Phase 1: GEMM  S_log2[i][j] = (x_i . y_j) * log2(e)/T ----
// 256x256 tile, 256 blocks (1/CU, ONE round), 512 thr (8 waves as 4x2),
// BK=64 double-buffered (128 KB LDS). Per wave 64x128 output:
// 12 ds_read_b128 : 32 MFMA per ks. All addresses hoisted; in-loop work is
// 2 v_add + 12 ds_read + 32 MFMA per ks. Swapped-operand MFMA (validated
// R4/R5): S-row <- Af's l15 row, S-col <- Bf row base + lg*4+v.
__global__ __launch_bounds__(512, 2) void cl_gemm2(const u16* __restrict__ xb,
                                                   const u16* __restrict__ yb,
                                                   u16* __restrict__ Sl) {
  __shared__ u16 As[2][256 * 64];   // 2 x 32 KB
  __shared__ u16 Bs[2][256 * 64];   // 2 x 32 KB  -> 128 KB total
  const int tid  = threadIdx.x;
  const int lane = tid & 63;
  const int wv   = tid >> 6;        // 0..7
  const int l15  = lane & 15;
  const int lg   = lane >> 4;       // 0..3
  const int wr   = wv >> 1;         // 0..3 (64-row group)
  const int wc   = wv & 1;          // 0..1 (128-col group)
  int bid = (int)blockIdx.x;
  bid = (bid & 7) * 32 + (bid >> 3);          // XCD swizzle (256 % 8 == 0)
  const int brow = (bid >> 4) << 8;
  const int bcol = (bid & 15) << 8;

  // Staging: panel = 256 rows x 128 B; 32 chunks of 1 KB (8 rows each).
  // Wave wv handles chunks {wv + 8i}, i<4. Pre-swizzled SOURCE column so the
  // linear LDS write + XOR'd ds_read form the same involution (rule 21).
  const int rsub = (wv << 3) + (lane >> 3);                  // + i*64 later
  const u32 cs0  = (u32)(((lane & 7) << 4) ^ ((lane >> 3) << 4));
  const char* aBase = (const char*)xb + ((size_t)(brow + rsub) << 9) + cs0;
  const char* bBase = (const char*)yb + ((size_t)(bcol + rsub) << 9) + cs0;
  const u32 dstOff = (u32)((wv << 10) + lane * 16);

  auto stage = [&](u16* panel, const char* base, int kt) {
#pragma unroll
    for (int i = 0; i < 4; ++i) {
      const char* g = base + i * 32768 + (kt << 7);
      auto lp = (__attribute__((address_space(3))) u32*)
                  ((char*)panel + i * 8192 + dstOff);
      __builtin_amdgcn_global_load_lds(
          (const __attribute__((address_space(1))) u32*)g, lp, 16, 0, 0);
    }
  };

  // Hoisted read offsets. ra&7 == l15&7 (row strides are multiples of 8).
  const u32 rowOffA = (u32)((((wr << 6) + l15) << 7));
  const u32 rowOffB = (u32)((((wc << 7) + l15) << 7));
  u32 colk[2];
#pragma unroll
  for (int ks = 0; ks < 2; ++ks)
    colk[ks] = (u32)(((ks << 6) + (lg << 4)) ^ ((l15 & 7) << 4));

  f32x4 acc[4][8] = {};

  stage(As[0], aBase, 0);
  stage(Bs[0], bBase, 0);
  __syncthreads();

#pragma unroll 1
  for (int kt = 0; kt < 4; ++kt) {
    if (kt < 3) {
      stage(As[(kt + 1) & 1], aBase, kt + 1);
      stage(Bs[(kt + 1) & 1], bBase, kt + 1);
    }
    const char* Ap = (const char*)As[kt & 1];
    const char* Bp = (const char*)Bs[kt & 1];
#pragma unroll
    for (int ks = 0; ks < 2; ++ks) {
      bf16x8 Af[4], Bf[8];
      const char* ap = Ap + rowOffA + colk[ks];
      const char* bp = Bp + rowOffB + colk[ks];
#pragma unroll
      for (int mi = 0; mi < 4; ++mi) Af[mi] = *(const bf16x8*)(ap + mi * 2048);
#pragma unroll
      for (int ni = 0; ni < 8; ++ni) Bf[ni] = *(const bf16x8*)(bp + ni * 2048);
#pragma unroll
      for (int mi = 0; mi < 4; ++mi)
#pragma unroll
        for (int ni = 0; ni < 8; ++ni)
          acc[mi][ni] = __builtin_amdgcn_mfma_f32_16x16x32_bf16(
              Bf[ni], Af[mi], acc[mi][ni], 0, 0, 0);   // swapped operands
    }
    __syncthreads();
  }

  // Packed 8-B stores; mapping validated in R4/R5.
#pragma unroll
  for (int mi = 0; mi < 4; ++mi)
#pragma unroll
    for (int ni = 0; ni < 8; ++ni) {
      u16x4 o;
#pragma unroll
      for (int v = 0; v < 4; ++v) o[v] = f2bf(acc[mi][ni][v] * SCALE);
      const int rs = brow + (wr << 6) + (mi << 4) + l15;
      const int cs = bcol + (wc << 7) + (ni << 4) + (lg << 2);
      *(u16x4*)(Sl + (size_t)rs * B_SZ + cs) = o;
    }
}

// ---------------- Phase 2: per-row cumsum + logs (R2-proven) ---------------
__global__ __launch_bounds__(256) void cl_scan(const u16* __restrict__ Sl,
                                               float* __restrict__ partials) {
  __shared__ float wtot[4];
  __shared__ float red2[4];
  const int row  = (int)blockIdx.x;
  const int tid  = threadIdx.x;
  const int lane = tid & 63;
  const int wv   = tid >> 6;

  const u16* rp = Sl + (size_t)row * B_SZ + tid * 16;
  s16x8 a = *(const s16x8*)rp;
  s16x8 b = *(const s16x8*)(rp + 8);
  float t[16], p[16];
  float run = 0.f;
#pragma unroll
  for (int j = 0; j < 8; ++j) { t[j] = bf2f((u16)a[j]); t[8 + j] = bf2f((u16)b[j]); }
#pragma unroll
  for (int j = 0; j < 16; ++j) { run += __builtin_amdgcn_exp2f(t[j]); p[j] = run; }

  float s = run;
#pragma unroll
  for (int d = 1; d < 64; d <<= 1) {          // inclusive scan over 64 lanes
    float u = __shfl_up(s, (unsigned)d, 64);
    if (lane >= d) s += u;
  }
  if (lane == 63) wtot[wv] = s;
  __syncthreads();
  float off = 0.f;
#pragma unroll
  for (int w = 0; w < 4; ++w) if (w < wv) off += wtot[w];
  const float excl = off + (s - run);

  float lacc = 0.f;
  const int c0 = tid * 16;
#pragma unroll
  for (int j = 0; j < 16; ++j)
    lacc += __builtin_amdgcn_logf(excl + p[j] + (float)(B_SZ - 1 - (c0 + j)));
  if ((row >> 4) == tid) lacc -= (float)(B_SZ - row) * t[row & 15];
  lacc *= LN2F;

#pragma unroll
  for (int d = 1; d < 64; d <<= 1) lacc += __shfl_xor(lacc, d, 64);
  if (lane == 0) red2[wv] = lacc;
  __syncthreads();
  if (tid == 0)
    partials[row] = (red2[0] + red2[1]) + (red2[2] + red2[3]);
}

__global__ __launch_bounds__(256) void cl_final(const float* __restrict__ p,
                                                float* __restrict__ out) {
  __shared__ float red[256];
  const int tid = threadIdx.x;
  float s = 0.f;
#pragma unroll
  for (int k = 0; k < 16; ++k) s += p[tid + 256 * k];
  red[tid] = s;
  __syncthreads();
#pragma unroll
  for (int o = 128; o > 0; o >>= 1) {
    if (tid < o) red[tid] += red[tid + o];
    __syncthreads();
  }
  if (tid == 0) out[0] = red[0];
}

// ---------------- Fallback (R1 fused kernel, known-good) -------------------
template<bool BF>
__global__ __launch_bounds__(256) void cl_main(const float* __restrict__ x,
                                               const float* __restrict__ y,
                                               const u16* __restrict__ xb,
                                               const u16* __restrict__ yb,
                                               float* __restrict__ partials) {
  __shared__ float st[16][68];
  __shared__ float red[256];
  const int tid  = threadIdx.x;
  const int lane = tid & 63;
  const int wv   = tid >> 6;
  const int l15  = lane & 15;
  const int lg   = lane >> 4;
  const int i0   = blockIdx.x * 16;

  bf16x8 A[8];
  {
    const size_t base = (size_t)(i0 + l15) * D_SZ + (lg << 3);
#pragma unroll
    for (int ks = 0; ks < 8; ++ks)
      A[ks] = ld8<BF>(xb + base + ks * 32, x + base + ks * 32);
  }

  float lacc = 0.f, carry = 0.f;

  auto load_b = [&](bf16x8 (&F)[8], int t) {
    const size_t jb = (size_t)(t * 64 + (wv << 4) + l15) * D_SZ + (lg << 3);
#pragma unroll
    for (int ks = 0; ks < 8; ++ks)
      F[ks] = ld8<BF>(yb + jb + ks * 32, y + jb + ks * 32);
  };

  auto body = [&](bf16x8 (&F)[8], int t) {
    f32x4 acc = {0.f, 0.f, 0.f, 0.f};
#pragma unroll
    for (int ks = 0; ks < 8; ++ks)
      acc = __builtin_amdgcn_mfma_f32_16x16x32_bf16(A[ks], F[ks], acc, 0, 0, 0);
    __syncthreads();
    const int colg = t * 64 + (wv << 4) + l15;
#pragma unroll
    for (int v = 0; v < 4; ++v) {
      float tv = acc[v] * SCALE;
      const int rowl = (lg << 2) + v;
      if (i0 + rowl == colg) lacc -= (float)(B_SZ - colg) * tv;
      st[rowl][(wv << 4) + l15] = tv;
    }
    __syncthreads();
    const int row = (wv << 2) + lg;
    f32x4 tv4 = *(const f32x4*)&st[row][l15 << 2];
    float e0 = __builtin_amdgcn_exp2f(tv4[0]);
    float e1 = __builtin_amdgcn_exp2f(tv4[1]);
    float e2 = __builtin_amdgcn_exp2f(tv4[2]);
    float e3 = __builtin_amdgcn_exp2f(tv4[3]);
    float p1 = e0 + e1, p2 = p1 + e2, p3 = p2 + e3;
    float s = p3;
#pragma unroll
    for (int d = 1; d < 16; d <<= 1) {
      float u = __shfl_up(s, (unsigned)d, 16);
      if (l15 >= d) s += u;
    }
    const float base = carry + (s - p3);
    const float c0 = (float)(B_SZ - 1 - (t * 64 + (l15 << 2)));
    lacc += __builtin_amdgcn_logf(base + e0 + c0)
          + __builtin_amdgcn_logf(base + p1 + (c0 - 1.f))
          + __builtin_amdgcn_logf(base + p2 + (c0 - 2.f))
          + __builtin_amdgcn_logf(base + p3 + (c0 - 3.f));
    carry += __shfl(s, 15, 16);
  };

  bf16x8 B0[8], B1[8];
  load_b(B0, 0);
#pragma unroll 1
  for (int t2 = 0; t2 < 32; ++t2) {
    const int t0 = t2 * 2;
    load_b(B1, t0 + 1);
    body(B0, t0);
    if (t0 + 2 < 64) load_b(B0, t0 + 2);
    body(B1, t0 + 1);
  }

  red[tid] = lacc * LN2F;
  __syncthreads();
#pragma unroll
  for (int o = 128; o > 0; o >>= 1) {
    if (tid < o) red[tid] += red[tid + o];
    __syncthreads();
  }
  if (tid == 0) partials[blockIdx.x] = red[0];
}

__global__ __launch_bounds__(256) void cl_reduce(const float* __restrict__ p,
                                                 float* __restrict__ out) {
  __shared__ float red[256];
  const int tid = threadIdx.x;
  red[tid] = p[tid];
  __syncthreads();
#pragma unroll
  for (int o = 128; o > 0; o >>= 1) {
    if (tid < o) red[tid] += red[tid + o];
    __syncthreads();
  }
  if (tid == 0) out[0] = red[0];
}

extern "C" void kernel_launch(void* const* d_in, const int* in_sizes, int n_in,
                              void* d_out, int out_size, void* d_ws, size_t ws_size,
                              hipStream_t stream) {
  const float* x = (const float*)d_in[0];
  const float* y = (const float*)d_in[1];
  float* out = (float*)d_out;
  const size_t BD = (size_t)B_SZ * D_SZ;

  // Layout: partials(16KB) | pad(256B) | xb(2MB) | yb(2MB) | Sl(32MB)
  float* partials = (float*)d_ws;
  u16* xb = (u16*)((char*)d_ws + 16384 + 256);
  u16* yb = xb + BD;
  u16* Sl = yb + BD;
  const size_t need = 16384 + 256 + 4 * BD + 2 * (size_t)B_SZ * B_SZ;

  if (ws_size >= need) {
    cl_convert<<<(int)(BD / 1024), 256, 0, stream>>>(x, y, xb, yb);
    cl_gemm2<<<256, 512, 0, stream>>>(xb, yb, Sl);
    cl_scan<<<B_SZ, 256, 0, stream>>>(Sl, partials);
    cl_final<<<1, 256, 0, stream>>>(partials, out);
  } else {
    // Fallback: R1 fused path (original layout: partials@0, xb@4KB)
    float* fpart = (float*)d_ws;
    u16* fxb = (u16*)((char*)d_ws + 4096);
    u16* fyb = fxb + BD;
    const size_t fneed = 4096 + 4 * BD;
    if (ws_size >= fneed) {
      cl_convert<<<(int)(BD / 1024), 256, 0, stream>>>(x, y, fxb, fyb);
      cl_main<true><<<B_SZ / 16, 256, 0, stream>>>(x, y, fxb, fyb, fpart);
    } else {
      cl_main<false><<<B_SZ / 16, 256, 0, stream>>>(x, y, fxb, fyb, fpart);
    }
    cl_reduce<<<1, 256, 0, stream>>>(fpart, out);
  }
}